// Round 7
// baseline (252.493 us; speedup 1.0000x reference)
//
#include <hip/hip_runtime.h>

#define BATCH 64
#define HH 512
#define WW 512
#define TH 32          // output rows per block strip
#define TW 256         // output cols per block tile
#define KS 11
#define PADK 5
#define LROW (TW + 2 * PADK)   // 266 float2 slots per staged row
#define NT 256                 // 1 column per thread
#define NBLK ((WW / TW) * (HH / TH) * BATCH)   // 2*16*64 = 2048
#define NPIX (64.0 * 512.0 * 512.0)

// R2 skeleton at HALF block size: 256 threads, 256-col tile + 5-col halos.
// Rationale (R6 post-mortem): per-row barriers in an 8-wave block serialize
// the whole CU when occupancy is 1-2 blocks; 4-wave blocks give finer
// occupancy granularity and cross-block barrier overlap.
// Per staged row: float2{a,b} single-row double-buffered staging (one
// prefetch pair issued before the barrier), 11 ds_read_b64, q=a^2+b^2 and
// p=ab in-flight, horizontal 11-tap -> (h1,h2,hq,hp), ring slot i%11 written
// ONCE (AGPR-friendly write-once pattern, proven in R2; RMW accs spill).
// Vertical 11-tap with static slot indices; SSIM; fused finalize.
__global__ void __launch_bounds__(NT)
ssim_main_kernel(const float* __restrict__ img1, const float* __restrict__ img2,
                 double* __restrict__ accum, unsigned int* __restrict__ counter,
                 float* __restrict__ out) {
  // Gaussian(sigma=1.5, K=11), normalized (fp64-precomputed).
  constexpr float G[KS] = {
      0.00102838f, 0.00759884f, 0.03600087f, 0.10936069f, 0.21300553f,
      0.26601172f, 0.21300553f, 0.10936069f, 0.03600087f, 0.00759884f,
      0.00102838f};

  const int c  = threadIdx.x;            // 0..255
  const int c0 = blockIdx.x * TW;        // col-tile origin (0 or 256)
  const int r0 = blockIdx.y * TH;        // row-strip origin
  const int b  = blockIdx.z;             // batch

  const float* __restrict__ p1 = img1 + (size_t)b * (HH * WW);
  const float* __restrict__ p2 = img2 + (size_t)b * (HH * WW);

  // Double-buffered single-row staging, 266 float2 slots (4.3 KB total).
  __shared__ float2 sh[2][LROW];

  // Halo assignment: threads c<10 also load one halo pixel.
  //   c in [0,5)  -> slot c        (cols c0-5 .. c0-1)
  //   c in [5,10) -> slot 256+c    (cols c0+256 .. c0+260)
  const int  hs      = (c < 5) ? c : (256 + c);
  const int  hcol    = c0 - PADK + hs;
  const bool hactive = (c < 10) && (hcol >= 0) && (hcol < WW);

  // Ring: slot (i % 11) holds h-conv of staged row i. Write-once, read-11x.
  float rA[KS], rB[KS], rQ[KS], rP[KS];
  float local = 0.f;

  // Prefetch staged row 0 (image row r0-5).
  float pa, pb, ha, hb;
  {
    const int rr = r0 - PADK;
    const bool v = (rr >= 0);
    const int off = rr * WW;
    pa = v ? p1[off + c0 + c] : 0.f;
    pb = v ? p2[off + c0 + c] : 0.f;
    ha = (v && hactive) ? p1[off + hcol] : 0.f;
    hb = (v && hactive) ? p2[off + hcol] : 0.f;
  }

  for (int ii = 0; ii < 4; ++ii) {       // dynamic outer: code fits I$
#pragma unroll
    for (int p = 0; p < KS; ++p) {
      const int i = ii * KS + p;         // i % 11 == p (static slot index)
      const int buf = i & 1;

      // Stage row i from prefetch regs (rows 42,43 staged but unused).
      sh[buf][PADK + c] = make_float2(pa, pb);
      if (c < 10) sh[buf][hs] = make_float2(ha, hb);

      // Prefetch row i+1 (loads in flight across the barrier + hconv).
      {
        const int rn = r0 - PADK + i + 1;
        const bool v = (rn >= 0) && (rn < HH);
        const int off = rn * WW;
        pa = v ? p1[off + c0 + c] : 0.f;
        pb = v ? p2[off + c0 + c] : 0.f;
        ha = (v && hactive) ? p1[off + hcol] : 0.f;
        hb = (v && hactive) ? p2[off + hcol] : 0.f;
      }

      __syncthreads();   // dbuf => one barrier per row (R2-proven ordering)

      // Horizontal 11-tap of {a, b, q=a^2+b^2, p=ab} (q,p in-flight).
      float h1 = 0.f, h2 = 0.f, hq = 0.f, hp = 0.f;
#pragma unroll
      for (int k = 0; k < KS; ++k) {
        const float2 v = sh[buf][c + k];
        const float q  = fmaf(v.x, v.x, v.y * v.y);
        const float pp = v.x * v.y;
        h1 = fmaf(G[k], v.x, h1);
        h2 = fmaf(G[k], v.y, h2);
        hq = fmaf(G[k], q,  hq);
        hp = fmaf(G[k], pp, hp);
      }
      rA[p] = h1; rB[p] = h2; rQ[p] = hq; rP[p] = hp;

      if (i >= 2 * PADK && i < TH + 2 * PADK) {   // uniform scalar branch
        // Vertical 11-tap: row (i-10+t) lives in slot (p+1+t)%11.
        float mu1 = 0.f, mu2 = 0.f, mq = 0.f, mp = 0.f;
#pragma unroll
        for (int t = 0; t < KS; ++t) {
          const int s = (p + 1 + t) % KS;  // static after unroll
          mu1 = fmaf(G[t], rA[s], mu1);
          mu2 = fmaf(G[t], rB[s], mu2);
          mq  = fmaf(G[t], rQ[s], mq);
          mp  = fmaf(G[t], rP[s], mp);
        }
        const float m1s = mu1 * mu1, m2s = mu2 * mu2, m12 = mu1 * mu2;
        const float t12 = m1s + m2s;
        const float s12 = mp - m12;          // sigma12
        const float sqq = mq - t12;          // sigma1^2 + sigma2^2
        const float C1 = 1e-4f, C2 = 9e-4f;
        const float num = fmaf(2.f, m12, C1) * fmaf(2.f, s12, C2);
        const float den = (t12 + C1) * (sqq + C2);
        local = fmaf(num, __builtin_amdgcn_rcpf(den), local);
      }
    }
  }

  // Block reduction: wave64 shuffle -> LDS -> one atomic per block.
#pragma unroll
  for (int off = 32; off > 0; off >>= 1) local += __shfl_down(local, off, 64);

  __shared__ float wsum[NT / 64];
  const int wave = threadIdx.x >> 6;
  const int lane = threadIdx.x & 63;
  if (lane == 0) wsum[wave] = local;
  __syncthreads();
  if (threadIdx.x == 0) {
    float s = 0.f;
#pragma unroll
    for (int w = 0; w < NT / 64; ++w) s += wsum[w];
    atomicAdd(accum, (double)s);
    __threadfence();
    const unsigned int n = atomicAdd(counter, 1u);
    if (n == NBLK - 1) {                 // last block finalizes (R5-proven)
      __threadfence();
      const double tot = atomicAdd(accum, 0.0);  // device-scope read
      out[0] = 1.0f - (float)(tot / NPIX);
    }
  }
}

extern "C" void kernel_launch(void* const* d_in, const int* in_sizes, int n_in,
                              void* d_out, int out_size, void* d_ws, size_t ws_size,
                              hipStream_t stream) {
  const float* img1 = (const float*)d_in[0];
  const float* img2 = (const float*)d_in[1];
  double* accum = (double*)d_ws;
  unsigned int* counter = (unsigned int*)((char*)d_ws + sizeof(double));
  hipMemsetAsync(d_ws, 0, 16, stream);

  dim3 grid(WW / TW, HH / TH, BATCH);
  ssim_main_kernel<<<grid, NT, 0, stream>>>(img1, img2, accum, counter,
                                            (float*)d_out);
}

// Round 8
// 203.676 us; speedup vs baseline: 1.2397x; 1.2397x over previous
//
#include <hip/hip_runtime.h>

#define BATCH 64
#define HH 512
#define WW 512
#define TH 32          // output rows per block strip
#define KS 11
#define PADK 5
#define NROW (TH + 2 * PADK)       // 42 staged rows per strip
#define NT 256                     // 2 columns per thread -> 512 cols
#define NBLK ((HH / TH) * BATCH)   // 1024 blocks
#define NPIX (64.0 * 512.0 * 512.0)
#define SLEN 528                   // floats/signal: 8 pad | 512 | 8 pad

// V-FIRST structure (R7 post-mortem: all h-first variants cost ~155k
// VALU-cyc/SIMD; the h-conv pays the 1.31 row-halo tax and 88+ B/px LDS).
// Each thread owns cols {2t, 2t+1}:
//  - raw a,b loaded global->register (coalesced b64), NO input LDS;
//  - 11-row ring of raw values (44 regs, write-once -> no spill; R5 lesson);
//  - vertical 11-tap with q=a^2+b^2, p=ab in flight (7 ops/tap);
//  - v-results {mu1,mu2,q,p} -> SoA float2 LDS exchange (stride 8 B,
//    conflict-free; R4 lesson: float4/32B strides conflict);
//  - ONE barrier, then horizontal 11-tap: 7 float2 reads/signal shared by
//    both cols (112 B/px vs 176), 4 fma/tap; SSIM; fused finalize.
// Prefetch distance = 2 rows (~2 iterations in flight across the barrier).
__global__ void __launch_bounds__(NT)
ssim_main_kernel(const float* __restrict__ img1, const float* __restrict__ img2,
                 double* __restrict__ accum, unsigned int* __restrict__ counter,
                 float* __restrict__ out) {
  // Gaussian(sigma=1.5, K=11), normalized (fp64-precomputed).
  constexpr float G[KS] = {
      0.00102838f, 0.00759884f, 0.03600087f, 0.10936069f, 0.21300553f,
      0.26601172f, 0.21300553f, 0.10936069f, 0.03600087f, 0.00759884f,
      0.00102838f};

  const int t  = threadIdx.x;        // owns cols 2t, 2t+1
  const int r0 = blockIdx.x * TH;
  const int b  = blockIdx.y;

  const float* __restrict__ p1 = img1 + (size_t)b * (HH * WW);
  const float* __restrict__ p2 = img2 + (size_t)b * (HH * WW);

  // v-result exchange: [parity][signal][8 pad | 512 | 8 pad]  (16.9 KB)
  __shared__ float vbuf[2][4][SLEN];
  if (t < 8) {
#pragma unroll
    for (int bi = 0; bi < 2; ++bi)
#pragma unroll
      for (int s = 0; s < 4; ++s) {
        vbuf[bi][s][t]          = 0.f;   // cols -8..-1
        vbuf[bi][s][8 + WW + t] = 0.f;   // cols 512..519
      }
  }
  // pads first read at i=10, after that iteration's barrier -> ordered.

  // Raw rings: slot (i%11) holds row i's {a,b} for the 2 cols. Write-once.
  float rA0[KS], rA1[KS], rB0[KS], rB1[KS];
  float local = 0.f;

  // Prefetch staged rows 0,1 (image rows r0-5, r0-4); guard low edge.
  float2 pfa_e, pfb_e, pfa_o, pfb_o;
  {
    const int rr = r0 - PADK;
    if (rr >= 0) {
      pfa_e = ((const float2*)(p1 + (size_t)rr * WW))[t];
      pfb_e = ((const float2*)(p2 + (size_t)rr * WW))[t];
    } else { pfa_e = make_float2(0.f, 0.f); pfb_e = make_float2(0.f, 0.f); }
  }
  {
    const int rr = r0 - PADK + 1;
    if (rr >= 0) {
      pfa_o = ((const float2*)(p1 + (size_t)rr * WW))[t];
      pfb_o = ((const float2*)(p2 + (size_t)rr * WW))[t];
    } else { pfa_o = make_float2(0.f, 0.f); pfb_o = make_float2(0.f, 0.f); }
  }

  for (int g = 0; g < 4; ++g) {
    // Buffer used at iter i = vbuf[i&1]; i&1 = (g&1)^(p&1).
    float (*bufE)[SLEN] = vbuf[g & 1];       // for even p
    float (*bufO)[SLEN] = vbuf[1 - (g & 1)]; // for odd p
#pragma unroll
    for (int p = 0; p < KS; ++p) {
      const int i = 11 * g + p;              // i % 11 == p (static)
      if (i < NROW) {                        // uniform: skip i=42,43
        // Consume prefetched row i into ring slot p (parity p&1: producer
        // was i-2, same local parity; cross-g flip fixed by swap below).
        {
          const float2 va = (p & 1) ? pfa_o : pfa_e;
          const float2 vb = (p & 1) ? pfb_o : pfb_e;
          rA0[p] = va.x; rA1[p] = va.y;
          rB0[p] = vb.x; rB1[p] = vb.y;
        }

        // Issue loads for row i+2 (in flight across ~2 iterations).
        if (i + 2 < NROW) {
          const int rr = r0 - PADK + i + 2;
          const bool v = (rr >= 0) && (rr < HH);   // block-uniform
          float2 na = make_float2(0.f, 0.f), nb = na;
          if (v) {
            na = ((const float2*)(p1 + (size_t)rr * WW))[t];
            nb = ((const float2*)(p2 + (size_t)rr * WW))[t];
          }
          if (p & 1) { pfa_o = na; pfb_o = nb; }
          else       { pfa_e = na; pfb_e = nb; }
        }

        if (i >= 2 * PADK) {                 // uniform: outputs exist
          // Vertical 11-tap on ring; staged row i-10+u is slot (p+1+u)%11.
          float m1x = 0.f, m1y = 0.f, m2x = 0.f, m2y = 0.f;
          float mqx = 0.f, mqy = 0.f, mpx = 0.f, mpy = 0.f;
#pragma unroll
          for (int u = 0; u < KS; ++u) {
            const int s = (p + 1 + u) % KS;  // static
            const float w = G[u];
            const float ax = rA0[s], bx = rB0[s];
            m1x = fmaf(w, ax, m1x);
            m2x = fmaf(w, bx, m2x);
            mqx = fmaf(w, fmaf(ax, ax, bx * bx), mqx);
            mpx = fmaf(w, ax * bx, mpx);
            const float ay = rA1[s], by = rB1[s];
            m1y = fmaf(w, ay, m1y);
            m2y = fmaf(w, by, m2y);
            mqy = fmaf(w, fmaf(ay, ay, by * by), mqy);
            mpy = fmaf(w, ay * by, mpy);
          }

          float (*B)[SLEN] = (p & 1) ? bufO : bufE;   // static select
          ((float2*)(B[0] + 8))[t] = make_float2(m1x, m1y);
          ((float2*)(B[1] + 8))[t] = make_float2(m2x, m2y);
          ((float2*)(B[2] + 8))[t] = make_float2(mqx, mqy);
          ((float2*)(B[3] + 8))[t] = make_float2(mpx, mpy);
          __syncthreads();   // dbuf: iter i+1 writes other buffer -> 1 barrier

          // Horizontal 11-tap. Col c lives at float idx 8+c.
          // px0=col 2t: tap k -> idx 2t+3+k; px1=col 2t+1: idx 2t+4+k.
          // float2 slot j = floats 2j,2j+1; read slots t+1..t+7 per signal.
          float h[8];   // {h1x,h1y,h2x,h2y,hqx,hqy,hpx,hpy}
#pragma unroll
          for (int s4 = 0; s4 < 4; ++s4) {
            const float2* S = (const float2*)(B[s4]);
            float2 f2[7];
#pragma unroll
            for (int j = 0; j < 7; ++j) f2[j] = S[t + 1 + j];
            float ax = 0.f, ay = 0.f;
#pragma unroll
            for (int k = 0; k < KS; ++k) {
              const float w = G[k];
              const int o0 = k + 1, o1 = k + 2;        // static
              const float e0 = (o0 & 1) ? f2[o0 / 2].y : f2[o0 / 2].x;
              const float e1 = (o1 & 1) ? f2[o1 / 2].y : f2[o1 / 2].x;
              ax = fmaf(w, e0, ax);
              ay = fmaf(w, e1, ay);
            }
            h[2 * s4]     = ax;
            h[2 * s4 + 1] = ay;
          }

          const float C1 = 1e-4f, C2 = 9e-4f;
#pragma unroll
          for (int px = 0; px < 2; ++px) {
            const float mu1 = h[0 + px], mu2 = h[2 + px];
            const float qq  = h[4 + px], pp  = h[6 + px];
            const float m1s = mu1 * mu1, m2s = mu2 * mu2, m12 = mu1 * mu2;
            const float t12 = m1s + m2s;
            const float s12 = pp - m12;        // sigma12
            const float sqq = qq - t12;        // sigma1^2 + sigma2^2
            const float num = fmaf(2.f, m12, C1) * fmaf(2.f, s12, C2);
            const float den = (t12 + C1) * (sqq + C2);
            local = fmaf(num, __builtin_amdgcn_rcpf(den), local);
          }
        }
      }
    }
    // 11 odd -> global parity flips each g: swap prefetch reg pairs.
    {
      float2 tmp;
      tmp = pfa_e; pfa_e = pfa_o; pfa_o = tmp;
      tmp = pfb_e; pfb_e = pfb_o; pfb_o = tmp;
    }
  }

  // Block reduction: wave64 shuffle -> LDS -> one atomic per block.
#pragma unroll
  for (int off = 32; off > 0; off >>= 1) local += __shfl_down(local, off, 64);

  __shared__ float wsum[NT / 64];
  const int wave = threadIdx.x >> 6;
  const int lane = threadIdx.x & 63;
  if (lane == 0) wsum[wave] = local;
  __syncthreads();
  if (threadIdx.x == 0) {
    float s = 0.f;
#pragma unroll
    for (int w = 0; w < NT / 64; ++w) s += wsum[w];
    atomicAdd(accum, (double)s);
    __threadfence();
    const unsigned int n = atomicAdd(counter, 1u);
    if (n == NBLK - 1) {                 // last block finalizes (R5-proven)
      __threadfence();
      const double tot = atomicAdd(accum, 0.0);  // device-scope read
      out[0] = 1.0f - (float)(tot / NPIX);
    }
  }
}

extern "C" void kernel_launch(void* const* d_in, const int* in_sizes, int n_in,
                              void* d_out, int out_size, void* d_ws, size_t ws_size,
                              hipStream_t stream) {
  const float* img1 = (const float*)d_in[0];
  const float* img2 = (const float*)d_in[1];
  double* accum = (double*)d_ws;
  unsigned int* counter = (unsigned int*)((char*)d_ws + sizeof(double));
  hipMemsetAsync(d_ws, 0, 16, stream);

  dim3 grid(HH / TH, BATCH);
  ssim_main_kernel<<<grid, NT, 0, stream>>>(img1, img2, accum, counter,
                                            (float*)d_out);
}